// Round 17
// baseline (926.958 us; speedup 1.0000x reference)
//
#include <hip/hip_runtime.h>

#define LNUM 4
#define DMODEL 1024
#define NHEAD 16
#define FDIM 4096
#define BATCH 4
#define SEQ 1024
#define HDIM 64
#define KBAND 8
#define MROWS (BATCH * SEQ)

typedef __attribute__((ext_vector_type(8))) __bf16 bf16x8;
typedef __attribute__((ext_vector_type(4))) float f32x4;
typedef __attribute__((ext_vector_type(8))) unsigned short u16x8;

__device__ __forceinline__ unsigned short f2bf(float f) {
  unsigned int u = __builtin_bit_cast(unsigned int, f);
  u = u + 0x7fffu + ((u >> 16) & 1u);
  return (unsigned short)(u >> 16);
}
__device__ __forceinline__ float bf2f(unsigned short h) {
  unsigned int u = ((unsigned int)h) << 16;
  return __builtin_bit_cast(float, u);
}

#define GLOAD16(gp, lp)                                                        \
  __builtin_amdgcn_global_load_lds(                                            \
      (const __attribute__((address_space(1))) void*)(gp),                     \
      (__attribute__((address_space(3))) void*)(lp), 16, 0, 0)

// ---------------- fp32 -> bf16 conversion -----------------------------------
__global__ __launch_bounds__(256) void cvt_bf16(const float* __restrict__ in,
                                                unsigned short* __restrict__ out,
                                                long n) {
  long i = ((long)blockIdx.x * 256 + threadIdx.x) * 4;
  if (i + 3 < n) {
    float4 v = *reinterpret_cast<const float4*>(in + i);
    ushort4 o;
    o.x = f2bf(v.x);
    o.y = f2bf(v.y);
    o.z = f2bf(v.z);
    o.w = f2bf(v.w);
    *reinterpret_cast<ushort4*>(out + i) = o;
  }
}

// ---------------- 128x128 bf16 GEMM, BK=32 dbuf + counted vmcnt -------------
// R17 = R16 (super-tile XCD swizzle, 25MB FETCH verified) + R11's counted
// vmcnt double-buffer. R12's dbuf regression was diagnosed as L2 thrash
// (FETCH 106MB) under the OLD bm-fastest swizzle (53MB baseline); super-tile
// removed that confound (25MB), so the 2-tile in-flight window should now
// fit L2. Per tile: STAGE(t+1 -> buf^1, 4 gloads/wave); vmcnt(4) [tile t
// landed; t+1 stays in flight across the barrier]; s_barrier; 8 ds_read +
// 16 MFMA; s_barrier. Ledger: 8 outstanding after STAGE, vmcnt(4) retires
// exactly tile t's 4. Race: compute(t) reads drain before end-barrier
// (MFMAs consume them in order); stage(t+2) writes after it. Verified
// correct in R12 (passed, absmax 0.031).
// T2 granule swizzle for 64B rows (R9-verified): stored (row,g) holds
// source granule g^((row>>1)&3); read quad = kg^((fr>>1)&3).
// Epilogue: wave-private LDS transpose, full 64B-line stores (R9-verified).
// blockIdx.z = K-split (range [z*Ks,(z+1)*Ks)); Ks % 32 == 0.
// EPI: 0 = bf16 (+bias), 1 = bf16 (+bias, exact gelu),
//      2 = bf16 PARTIAL slab per z (bias only z==0).
template <int EPI>
__global__ __launch_bounds__(256, 4) void gemm128(const unsigned short* __restrict__ A,
                                                  const unsigned short* __restrict__ W,
                                                  const float* __restrict__ bias,
                                                  unsigned short* __restrict__ Cout,
                                                  int Ndim, int Kdim, int Ks) {
  __shared__ unsigned short SH[16384];  // [buf][A 4096 | B 4096] u16
  const int tid = threadIdx.x;
  const int wave = tid >> 6;
  const int lane = tid & 63;

  // bijective XCD chunked swizzle (m204) + 8x8 super-tile inner order
  // (R16-verified: per-XCD working set ~4MB = L2; FETCH 53->25MB).
  const int gx = gridDim.x, gy = gridDim.y;
  const int nwg = gx * gy;
  const int lin = blockIdx.x + blockIdx.y * gx;
  const int q8 = nwg >> 3, r8 = nwg & 7;
  const int xcd = lin & 7, cidx = lin >> 3;
  const int cbase = (xcd < r8) ? xcd * (q8 + 1) : r8 * (q8 + 1) + (xcd - r8) * q8;
  const int swz = cbase + cidx;
  const int sup = swz >> 6, inn = swz & 63;       // super-tile = 64 wg
  const int sbm = sup % (gy >> 3);
  const int sbn = sup / (gy >> 3);
  const int bm0 = (sbm * 8 + (inn & 7)) * 128;
  const int bn0 = (sbn * 8 + (inn >> 3)) * 128;
  const int kz0 = blockIdx.z * Ks;

  // staging: tile 128r x 32k = 8KB/matrix = 256 thr x 2 instrs x 16B.
  // thread t -> row t>>2, LDS granule t&3; source granule (t&3)^((t>>3)&3).
  const int r0 = tid >> 2;
  const int c0 = (((tid & 3) ^ ((tid >> 3) & 3)) << 3);
  const unsigned short* gA = A + (size_t)(bm0 + r0) * Kdim + kz0 + c0;
  const unsigned short* gB = W + (size_t)(bn0 + r0) * Kdim + kz0 + c0;
  const size_t rowstep = (size_t)64 * Kdim;

  f32x4 acc[4][4] = {};

  const int wr = (wave >> 1) * 64;  // wave row origin in tile
  const int wc = (wave & 1) * 64;   // wave col origin in tile
  const int fr = lane & 15;
  const int kg = lane >> 4;                        // K granule 0..3
  const int kofs = ((kg ^ ((fr >> 1) & 3)) << 3);  // read-side swizzled col

#define STAGE(buf, kt)                                                         \
  do {                                                                         \
    const unsigned short* pa = gA + (size_t)(kt) * 32;                         \
    const unsigned short* pb = gB + (size_t)(kt) * 32;                         \
    unsigned short* la = &SH[(buf) * 8192];                                    \
    unsigned short* lb = &SH[(buf) * 8192 + 4096];                             \
    GLOAD16(pa, la + wave * 512);                                              \
    GLOAD16(pa + rowstep, la + 2048 + wave * 512);                             \
    GLOAD16(pb, lb + wave * 512);                                              \
    GLOAD16(pb + rowstep, lb + 2048 + wave * 512);                             \
  } while (0)

  const int nt = Ks >> 5;
  STAGE(0, 0);
  for (int t = 0; t < nt; ++t) {
    const int cur = t & 1;
    if (t + 1 < nt) {
      STAGE(cur ^ 1, t + 1);
      asm volatile("s_waitcnt vmcnt(4)" ::: "memory");  // tile t landed only
    } else {
      asm volatile("s_waitcnt vmcnt(0)" ::: "memory");
    }
    __builtin_amdgcn_s_barrier();
    asm volatile("" ::: "memory");  // compiler fence (no instruction)
    const unsigned short* As = &SH[cur * 8192];
    const unsigned short* Bs = &SH[cur * 8192 + 4096];
    bf16x8 af[4], bfr[4];
#pragma unroll
    for (int i = 0; i < 4; ++i)
      af[i] = *reinterpret_cast<const bf16x8*>(&As[(wr + i * 16 + fr) * 32 + kofs]);
#pragma unroll
    for (int j = 0; j < 4; ++j)
      bfr[j] = *reinterpret_cast<const bf16x8*>(&Bs[(wc + j * 16 + fr) * 32 + kofs]);
#pragma unroll
    for (int i = 0; i < 4; ++i)
#pragma unroll
      for (int j = 0; j < 4; ++j)
        acc[i][j] = __builtin_amdgcn_mfma_f32_16x16x32_bf16(af[i], bfr[j], acc[i][j], 0, 0, 0);
    asm volatile("" ::: "memory");  // compiler fence
    __builtin_amdgcn_s_barrier();   // join reads before buf overwrite
  }
#undef STAGE

  // ---- transposed epilogue (R9/R10-verified; LDS reused after final barrier) ----
  // C/D layout: col = lane&15, row = (lane>>4)*4 + reg (m89/m91).
  const int rr = (lane >> 4) * 4;
  const int cc = lane & 15;
  const bool addb = (EPI != 2) || (blockIdx.z == 0);
  unsigned short* outZ =
      Cout + (EPI == 2 ? (size_t)blockIdx.z * ((size_t)gy * 128) * Ndim : 0);
  float bv[4];
#pragma unroll
  for (int j = 0; j < 4; ++j)
    bv[j] = addb ? bias[bn0 + wc + j * 16 + cc] : 0.0f;

  unsigned short* lt = SH + wave * 1280;  // 2560 B per wave (32 rows x 40 u16)
#pragma unroll
  for (int rh = 0; rh < 2; ++rh) {        // row half: rows rh*32..+31
#pragma unroll
    for (int cp = 0; cp < 2; ++cp) {      // col pair: cols cp*32..+31
#pragma unroll
      for (int ii = 0; ii < 2; ++ii)
#pragma unroll
        for (int jj = 0; jj < 2; ++jj)
#pragma unroll
          for (int r = 0; r < 4; ++r) {
            float v = acc[rh * 2 + ii][cp * 2 + jj][r] + bv[cp * 2 + jj];
            if (EPI == 1) v = 0.5f * v * (1.0f + erff(v * 0.70710678118654752f));
            lt[(ii * 16 + rr + r) * 40 + jj * 16 + cc] = f2bf(v);
          }
      asm volatile("s_waitcnt lgkmcnt(0)" ::: "memory");  // wave-local RAW
      const int rl = lane >> 1;            // local row 0..31
      const int chalf = (lane & 1) * 16;   // col sub-half (16 u16 = 32 B)
      u16x8 o0 = *reinterpret_cast<const u16x8*>(&lt[rl * 40 + chalf]);
      u16x8 o1 = *reinterpret_cast<const u16x8*>(&lt[rl * 40 + chalf + 8]);
      const int m = bm0 + wr + rh * 32 + rl;
      const int n0 = bn0 + wc + cp * 32 + chalf;
      unsigned short* dst = outZ + (size_t)m * Ndim + n0;
      *reinterpret_cast<u16x8*>(dst) = o0;
      *reinterpret_cast<u16x8*>(dst + 8) = o1;
      asm volatile("s_waitcnt lgkmcnt(0)" ::: "memory");  // reads done pre-overwrite
    }
  }
}

// ---------------- banded attention: one wave per (b,h,q), lane = d ----------
__global__ __launch_bounds__(256) void attn_band(const unsigned short* __restrict__ qkv,
                                                 unsigned short* __restrict__ outp) {
  const int gw = blockIdx.x * 4 + (threadIdx.x >> 6);
  const int lane = threadIdx.x & 63;
  const int q = gw & (SEQ - 1);
  const int bh = gw >> 10;
  const int h = bh & (NHEAD - 1);
  const int b = bh >> 4;
  const size_t row0 = (size_t)(b * SEQ + q);
  const size_t stride = 3 * DMODEL;
  const float qv = bf2f(qkv[row0 * stride + h * HDIM + lane]);

  float sc[KBAND];
  float mx = -1e30f;
#pragma unroll
  for (int jj = 0; jj < KBAND; ++jj) {
    const int j = q + jj;
    const int jc = (j < SEQ) ? j : (SEQ - 1);
    float kv = bf2f(qkv[(size_t)(b * SEQ + jc) * stride + DMODEL + h * HDIM + lane]);
    float p = qv * kv;
#pragma unroll
    for (int m = 32; m; m >>= 1) p += __shfl_xor(p, m);
    p *= 0.125f;
    p = (j < SEQ) ? p : -1e30f;
    sc[jj] = p;
    mx = fmaxf(mx, p);
  }
  float denom = 0.f;
  float ov = 0.f;
#pragma unroll
  for (int jj = 0; jj < KBAND; ++jj) {
    const int j = q + jj;
    const int jc = (j < SEQ) ? j : (SEQ - 1);
    float p = __expf(sc[jj] - mx);
    p = (j < SEQ) ? p : 0.f;
    denom += p;
    ov += p * bf2f(qkv[(size_t)(b * SEQ + jc) * stride + 2 * DMODEL + h * HDIM + lane]);
  }
  ov /= denom;
  outp[row0 * DMODEL + h * HDIM + lane] = f2bf(ov);
}

// ---------------- residual(bf16, in-place) + split-K reduce + LayerNorm -----
__global__ __launch_bounds__(256) void add_ln(const float* __restrict__ srcf,
                                              unsigned short* __restrict__ xb,
                                              const unsigned short* __restrict__ part,
                                              int nz,
                                              const float* __restrict__ gw,
                                              const float* __restrict__ gb,
                                              float* __restrict__ outf) {
  const int row = blockIdx.x;
  const int tid = threadIdx.x;
  const size_t slab = (size_t)MROWS * DMODEL;
  unsigned short* xp = xb + (size_t)row * DMODEL;
  const unsigned short* pp = part + (size_t)row * DMODEL;
  float v[4];
  float s = 0.f, s2 = 0.f;
#pragma unroll
  for (int i = 0; i < 4; ++i) {
    const int idx = tid + i * 256;
    float a = srcf ? srcf[(size_t)row * DMODEL + idx] : bf2f(xp[idx]);
    for (int z = 0; z < nz; ++z) a += bf2f(pp[z * slab + idx]);
    v[i] = a;
    s += a;
    s2 += a * a;
  }
#pragma unroll
  for (int m = 32; m; m >>= 1) {
    s += __shfl_xor(s, m);
    s2 += __shfl_xor(s2, m);
  }
  __shared__ float wsm[8];
  const int wave = tid >> 6, lane = tid & 63;
  if (lane == 0) {
    wsm[wave] = s;
    wsm[4 + wave] = s2;
  }
  __syncthreads();
  s = wsm[0] + wsm[1] + wsm[2] + wsm[3];
  s2 = wsm[4] + wsm[5] + wsm[6] + wsm[7];
  const float mean = s * (1.f / DMODEL);
  const float var = s2 * (1.f / DMODEL) - mean * mean;
  const float rstd = rsqrtf(var + 1e-5f);
#pragma unroll
  for (int i = 0; i < 4; ++i) {
    const int idx = tid + i * 256;
    const float y = (v[i] - mean) * rstd * gw[idx] + gb[idx];
    xp[idx] = f2bf(y);
    if (outf) outf[(size_t)row * DMODEL + idx] = y;
  }
}

extern "C" void kernel_launch(void* const* d_in, const int* in_sizes, int n_in,
                              void* d_out, int out_size, void* d_ws, size_t ws_size,
                              hipStream_t stream) {
  const float* src  = (const float*)d_in[0];
  const float* Wqkv = (const float*)d_in[1];
  const float* bqkv = (const float*)d_in[2];
  const float* Wo   = (const float*)d_in[3];
  const float* bo   = (const float*)d_in[4];
  const float* W1   = (const float*)d_in[5];
  const float* b1   = (const float*)d_in[6];
  const float* W2   = (const float*)d_in[7];
  const float* b2   = (const float*)d_in[8];
  const float* ln1w = (const float*)d_in[9];
  const float* ln1b = (const float*)d_in[10];
  const float* ln2w = (const float*)d_in[11];
  const float* ln2b = (const float*)d_in[12];
  float* out = (float*)d_out;

  // workspace carve-up (~168 MB of 209.7 MB)
  char* p = (char*)d_ws;
  unsigned short* wqkv_b = (unsigned short*)p; p += (size_t)LNUM * 3072 * 1024 * 2;
  unsigned short* wo_b   = (unsigned short*)p; p += (size_t)LNUM * 1024 * 1024 * 2;
  unsigned short* w1_b   = (unsigned short*)p; p += (size_t)LNUM * 4096 * 1024 * 2;
  unsigned short* w2_b   = (unsigned short*)p; p += (size_t)LNUM * 1024 * 4096 * 2;
  unsigned short* xb     = (unsigned short*)p; p += (size_t)MROWS * DMODEL * 2;
  // region R: [qkvb 24MB | aob 8MB] aliased by [hb 32MB], then part 4x8MB bf16
  char* R = p;
  unsigned short* qkvb = (unsigned short*)R;
  unsigned short* aob  = (unsigned short*)(R + (size_t)MROWS * 3 * DMODEL * 2);
  unsigned short* hb   = (unsigned short*)R;
  unsigned short* part = (unsigned short*)(R + (size_t)MROWS * 4096 * 2);
  p = R + (size_t)MROWS * 4096 * 2 + (size_t)4 * MROWS * DMODEL * 2;
  if (ws_size < (size_t)(p - (char*)d_ws)) return;

  cvt_bf16<<<(long)LNUM * 3072 * 1024 / 1024, 256, 0, stream>>>(Wqkv, wqkv_b, (long)LNUM * 3072 * 1024);
  cvt_bf16<<<(long)LNUM * 1024 * 1024 / 1024, 256, 0, stream>>>(Wo, wo_b, (long)LNUM * 1024 * 1024);
  cvt_bf16<<<(long)LNUM * 4096 * 1024 / 1024, 256, 0, stream>>>(W1, w1_b, (long)LNUM * 4096 * 1024);
  cvt_bf16<<<(long)LNUM * 1024 * 4096 / 1024, 256, 0, stream>>>(W2, w2_b, (long)LNUM * 1024 * 4096);
  cvt_bf16<<<(long)MROWS * DMODEL / 1024, 256, 0, stream>>>(src, xb, (long)MROWS * DMODEL);

  for (int l = 0; l < LNUM; ++l) {
    // QKV: [4096,1024] x [3072,1024]^T -> bf16 [4096,3072]; 768 blk (3/CU)
    gemm128<0><<<dim3(3072 / 128, MROWS / 128, 1), 256, 0, stream>>>(
        xb, wqkv_b + (size_t)l * 3072 * 1024, bqkv + l * 3072, qkvb, 3072, 1024, 1024);
    attn_band<<<(BATCH * NHEAD * SEQ) / 4, 256, 0, stream>>>(qkvb, aob);
    // Wo: split-K=2 (Ks=512) -> bf16 partials; 512 blk (2/CU)
    gemm128<2><<<dim3(1024 / 128, MROWS / 128, 2), 256, 0, stream>>>(
        aob, wo_b + (size_t)l * 1024 * 1024, bo + l * 1024, part, 1024, 1024, 512);
    // x = LN(x + p0 + p1); in-place bf16 residual (srcf only on layer 0)
    add_ln<<<MROWS, 256, 0, stream>>>(l == 0 ? src : nullptr, xb, part, 2,
                                      ln1w + l * DMODEL, ln1b + l * DMODEL, nullptr);
    // W1 + gelu: -> bf16 [4096,4096]; 1024 blk (4/CU)
    gemm128<1><<<dim3(FDIM / 128, MROWS / 128, 1), 256, 0, stream>>>(
        xb, w1_b + (size_t)l * 4096 * 1024, b1 + l * FDIM, hb, FDIM, 1024, 1024);
    // W2: split-K=4 (Ks=1024) -> bf16 partials; 1024 blk (4/CU)
    gemm128<2><<<dim3(1024 / 128, MROWS / 128, 4), 256, 0, stream>>>(
        hb, w2_b + (size_t)l * 1024 * 4096, b2 + l * 1024, part, 1024, 4096, 1024);
    // x = LN(x + sum p); final layer also writes f32 d_out
    add_ln<<<MROWS, 256, 0, stream>>>(nullptr, xb, part, 4,
                                      ln2w + l * DMODEL, ln2b + l * DMODEL,
                                      (l == LNUM - 1) ? out : nullptr);
  }
}

// Round 18
// 896.575 us; speedup vs baseline: 1.0339x; 1.0339x over previous
//
#include <hip/hip_runtime.h>

#define LNUM 4
#define DMODEL 1024
#define NHEAD 16
#define FDIM 4096
#define BATCH 4
#define SEQ 1024
#define HDIM 64
#define KBAND 8
#define MROWS (BATCH * SEQ)

typedef __attribute__((ext_vector_type(8))) __bf16 bf16x8;
typedef __attribute__((ext_vector_type(4))) float f32x4;
typedef __attribute__((ext_vector_type(8))) unsigned short u16x8;

__device__ __forceinline__ unsigned short f2bf(float f) {
  unsigned int u = __builtin_bit_cast(unsigned int, f);
  u = u + 0x7fffu + ((u >> 16) & 1u);
  return (unsigned short)(u >> 16);
}
__device__ __forceinline__ float bf2f(unsigned short h) {
  unsigned int u = ((unsigned int)h) << 16;
  return __builtin_bit_cast(float, u);
}

#define GLOAD16(gp, lp)                                                        \
  __builtin_amdgcn_global_load_lds(                                            \
      (const __attribute__((address_space(1))) void*)(gp),                     \
      (__attribute__((address_space(3))) void*)(lp), 16, 0, 0)

// ---------------- fp32 -> bf16 conversion -----------------------------------
__global__ __launch_bounds__(256) void cvt_bf16(const float* __restrict__ in,
                                                unsigned short* __restrict__ out,
                                                long n) {
  long i = ((long)blockIdx.x * 256 + threadIdx.x) * 4;
  if (i + 3 < n) {
    float4 v = *reinterpret_cast<const float4*>(in + i);
    ushort4 o;
    o.x = f2bf(v.x);
    o.y = f2bf(v.y);
    o.z = f2bf(v.z);
    o.w = f2bf(v.w);
    *reinterpret_cast<ushort4*>(out + i) = o;
  }
}

// ---------------- 128x128 bf16 GEMM, BK=64 single-buffer (R16 exact) --------
// Measured best small-N config (R16: 866us total). R17's counted-vmcnt dbuf
// regressed (57 vs 51us, MfmaUtil 24 vs 27): BK=32 halves MFMA/barrier and
// doubles barrier frequency — schedule axis closed (6 variants all lose to
// drain-0 + TLP). Used for Wo / W2 (N=1024, split-K).
template <int EPI>
__global__ __launch_bounds__(256, 4) void gemm128(const unsigned short* __restrict__ A,
                                                  const unsigned short* __restrict__ W,
                                                  const float* __restrict__ bias,
                                                  unsigned short* __restrict__ Cout,
                                                  int Ndim, int Kdim, int Ks) {
  __shared__ unsigned short SH[16384];  // As=SH[0:8192], Bs=SH[8192:16384]
  unsigned short* As = SH;
  unsigned short* Bs = SH + 8192;
  const int tid = threadIdx.x;
  const int wave = tid >> 6;
  const int lane = tid & 63;

  // bijective XCD chunked swizzle (m204) + 8x8 super-tile inner order
  // (R16-verified: per-XCD working set ~4MB = L2; FETCH 53->25MB).
  const int gx = gridDim.x, gy = gridDim.y;
  const int nwg = gx * gy;
  const int lin = blockIdx.x + blockIdx.y * gx;
  const int q8 = nwg >> 3, r8 = nwg & 7;
  const int xcd = lin & 7, cidx = lin >> 3;
  const int cbase = (xcd < r8) ? xcd * (q8 + 1) : r8 * (q8 + 1) + (xcd - r8) * q8;
  const int swz = cbase + cidx;
  const int sup = swz >> 6, inn = swz & 63;       // super-tile = 64 wg
  const int sbm = sup % (gy >> 3);
  const int sbn = sup / (gy >> 3);
  const int bm0 = (sbm * 8 + (inn & 7)) * 128;
  const int bn0 = (sbn * 8 + (inn >> 3)) * 128;
  const int kz0 = blockIdx.z * Ks;

  const int r0 = tid >> 3;                               // 0..31
  const int c0 = (((tid & 7) ^ ((tid >> 4) & 7)) << 3);  // swizzled col elem
  const unsigned short* gA = A + (size_t)(bm0 + r0) * Kdim + kz0 + c0;
  const unsigned short* gB = W + (size_t)(bn0 + r0) * Kdim + kz0 + c0;
  const size_t rs32 = (size_t)32 * Kdim;

  f32x4 acc[4][4] = {};

  const int wr = (wave >> 1) * 64;
  const int wc = (wave & 1) * 64;
  const int fr = lane & 15;
  const int rkey = (fr >> 1) & 7;

  const int nt = Ks >> 6;
  for (int t = 0; t < nt; ++t) {
#pragma unroll
    for (int i = 0; i < 4; ++i) {
      GLOAD16(gA + i * rs32, &As[i * 2048 + wave * 512]);
      GLOAD16(gB + i * rs32, &Bs[i * 2048 + wave * 512]);
    }
    gA += 64;
    gB += 64;
    __syncthreads();
#pragma unroll
    for (int ks = 0; ks < 2; ++ks) {
      const int kg0 = (lane >> 4) + 4 * ks;
      const int kofs = ((kg0 ^ rkey) << 3);
      bf16x8 af[4], bfr[4];
#pragma unroll
      for (int i = 0; i < 4; ++i)
        af[i] = *reinterpret_cast<const bf16x8*>(&As[(wr + i * 16 + fr) * 64 + kofs]);
#pragma unroll
      for (int j = 0; j < 4; ++j)
        bfr[j] = *reinterpret_cast<const bf16x8*>(&Bs[(wc + j * 16 + fr) * 64 + kofs]);
#pragma unroll
      for (int i = 0; i < 4; ++i)
#pragma unroll
        for (int j = 0; j < 4; ++j)
          acc[i][j] = __builtin_amdgcn_mfma_f32_16x16x32_bf16(af[i], bfr[j], acc[i][j], 0, 0, 0);
    }
    __syncthreads();
  }

  const int rr = (lane >> 4) * 4;
  const int cc = lane & 15;
  const bool addb = (EPI != 2) || (blockIdx.z == 0);
  unsigned short* outZ =
      Cout + (EPI == 2 ? (size_t)blockIdx.z * ((size_t)gy * 128) * Ndim : 0);
  float bv[4];
#pragma unroll
  for (int j = 0; j < 4; ++j)
    bv[j] = addb ? bias[bn0 + wc + j * 16 + cc] : 0.0f;

  unsigned short* lt = SH + wave * 1280;
#pragma unroll
  for (int rh = 0; rh < 2; ++rh) {
#pragma unroll
    for (int cp = 0; cp < 2; ++cp) {
#pragma unroll
      for (int ii = 0; ii < 2; ++ii)
#pragma unroll
        for (int jj = 0; jj < 2; ++jj)
#pragma unroll
          for (int r = 0; r < 4; ++r) {
            float v = acc[rh * 2 + ii][cp * 2 + jj][r] + bv[cp * 2 + jj];
            if (EPI == 1) v = 0.5f * v * (1.0f + erff(v * 0.70710678118654752f));
            lt[(ii * 16 + rr + r) * 40 + jj * 16 + cc] = f2bf(v);
          }
      asm volatile("s_waitcnt lgkmcnt(0)" ::: "memory");
      const int rl = lane >> 1;
      const int chalf = (lane & 1) * 16;
      u16x8 o0 = *reinterpret_cast<const u16x8*>(&lt[rl * 40 + chalf]);
      u16x8 o1 = *reinterpret_cast<const u16x8*>(&lt[rl * 40 + chalf + 8]);
      const int m = bm0 + wr + rh * 32 + rl;
      const int n0 = bn0 + wc + cp * 32 + chalf;
      unsigned short* dst = outZ + (size_t)m * Ndim + n0;
      *reinterpret_cast<u16x8*>(dst) = o0;
      *reinterpret_cast<u16x8*>(dst + 8) = o1;
      asm volatile("s_waitcnt lgkmcnt(0)" ::: "memory");
    }
  }
}

// ---------------- 256x128 bf16 GEMM, BK=64 single-buffer --------------------
// R18: per-wave-work axis. Same drain-0 structure as gemm128, but 256x128
// block: 4 waves x (128x64 out), acc 8x4 f32x4. 64 MFMA per barrier-pair
// (2x gemm128) vs ~same exposed stall per iter -> stall fraction ~45%->~30%.
// LDS 48KB -> 2-3 blocks/CU; R8 measured 2/CU delivers same throughput as
// 4/CU, so TLP loss is pre-paid. VGPR ~200 (acc 128 + frags) -> 2 waves/SIMD.
// Super-tile: 4bm x 8bn = 32wg -> per-XCD A 2MB + B 2MB = L2. Requires
// gy % 4 == 0, gx % 8 == 0 (QKV 24x16, W1 32x16 OK). Used for QKV / W1.
template <int EPI>
__global__ __launch_bounds__(256, 2) void gemm256x128(const unsigned short* __restrict__ A,
                                                      const unsigned short* __restrict__ W,
                                                      const float* __restrict__ bias,
                                                      unsigned short* __restrict__ Cout,
                                                      int Ndim, int Kdim, int Ks) {
  __shared__ unsigned short SH[24576];  // As [256][64]=16384, Bs [128][64]=8192
  unsigned short* As = SH;
  unsigned short* Bs = SH + 16384;
  const int tid = threadIdx.x;
  const int wave = tid >> 6;
  const int lane = tid & 63;

  // XCD chunked swizzle + 4x8 super-tile (A 2MB + B 2MB = 4MB = L2).
  const int gx = gridDim.x, gy = gridDim.y;
  const int nwg = gx * gy;
  const int lin = blockIdx.x + blockIdx.y * gx;
  const int q8 = nwg >> 3, r8 = nwg & 7;
  const int xcd = lin & 7, cidx = lin >> 3;
  const int cbase = (xcd < r8) ? xcd * (q8 + 1) : r8 * (q8 + 1) + (xcd - r8) * q8;
  const int swz = cbase + cidx;
  const int sup = swz >> 5, inn = swz & 31;       // super-tile = 32 wg
  const int sbm = sup % (gy >> 2);
  const int sbn = sup / (gy >> 2);
  const int bm0 = (sbm * 4 + (inn & 3)) * 256;
  const int bn0 = (sbn * 8 + (inn >> 2)) * 128;
  const int kz0 = blockIdx.z * Ks;

  // staging: A 256r x 64k = 32KB = 8 instrs; B 128r x 64k = 16KB = 4 instrs.
  // thread t -> row t>>3 (+32 per instr), source granule (t&7)^((t>>4)&7)
  // (key (row>>1)&7, invariant under row+32).
  const int r0 = tid >> 3;                               // 0..31
  const int c0 = (((tid & 7) ^ ((tid >> 4) & 7)) << 3);  // swizzled col elem
  const unsigned short* gA = A + (size_t)(bm0 + r0) * Kdim + kz0 + c0;
  const unsigned short* gB = W + (size_t)(bn0 + r0) * Kdim + kz0 + c0;
  const size_t rs32 = (size_t)32 * Kdim;

  f32x4 acc[8][4] = {};

  const int wm = wave >> 1;         // 0..1
  const int wn = wave & 1;          // 0..1
  const int wr = wm * 128;          // wave row origin (128 rows/wave)
  const int wc = wn * 64;           // wave col origin (64 cols/wave)
  const int fr = lane & 15;
  const int rkey = (fr >> 1) & 7;

  const int nt = Ks >> 6;
  for (int t = 0; t < nt; ++t) {
#pragma unroll
    for (int i = 0; i < 8; ++i)
      GLOAD16(gA + i * rs32, &As[i * 2048 + wave * 512]);
#pragma unroll
    for (int i = 0; i < 4; ++i)
      GLOAD16(gB + i * rs32, &Bs[i * 2048 + wave * 512]);
    gA += 64;
    gB += 64;
    __syncthreads();  // drains vmcnt(0): tile staged
#pragma unroll
    for (int ks = 0; ks < 2; ++ks) {
      const int kg0 = (lane >> 4) + 4 * ks;
      const int kofs = ((kg0 ^ rkey) << 3);
      bf16x8 af[8], bfr[4];
#pragma unroll
      for (int i = 0; i < 8; ++i)
        af[i] = *reinterpret_cast<const bf16x8*>(&As[(wr + i * 16 + fr) * 64 + kofs]);
#pragma unroll
      for (int j = 0; j < 4; ++j)
        bfr[j] = *reinterpret_cast<const bf16x8*>(&Bs[(wc + j * 16 + fr) * 64 + kofs]);
#pragma unroll
      for (int i = 0; i < 8; ++i)
#pragma unroll
        for (int j = 0; j < 4; ++j)
          acc[i][j] = __builtin_amdgcn_mfma_f32_16x16x32_bf16(af[i], bfr[j], acc[i][j], 0, 0, 0);
    }
    __syncthreads();  // reads done before next stage overwrites
  }

  // ---- transposed epilogue (R9 pattern; 4 row-halves per wave) ----
  const int rr = (lane >> 4) * 4;
  const int cc = lane & 15;
  const bool addb = (EPI != 2) || (blockIdx.z == 0);
  unsigned short* outZ =
      Cout + (EPI == 2 ? (size_t)blockIdx.z * ((size_t)gy * 256) * Ndim : 0);
  float bv[4];
#pragma unroll
  for (int j = 0; j < 4; ++j)
    bv[j] = addb ? bias[bn0 + wc + j * 16 + cc] : 0.0f;

  unsigned short* lt = SH + wave * 1280;  // 2560 B/wave, fits in As region
#pragma unroll
  for (int rh = 0; rh < 4; ++rh) {        // row quarter: rows rh*32..+31
#pragma unroll
    for (int cp = 0; cp < 2; ++cp) {      // col pair: cols cp*32..+31
#pragma unroll
      for (int ii = 0; ii < 2; ++ii)
#pragma unroll
        for (int jj = 0; jj < 2; ++jj)
#pragma unroll
          for (int r = 0; r < 4; ++r) {
            float v = acc[rh * 2 + ii][cp * 2 + jj][r] + bv[cp * 2 + jj];
            if (EPI == 1) v = 0.5f * v * (1.0f + erff(v * 0.70710678118654752f));
            lt[(ii * 16 + rr + r) * 40 + jj * 16 + cc] = f2bf(v);
          }
      asm volatile("s_waitcnt lgkmcnt(0)" ::: "memory");  // wave-local RAW
      const int rl = lane >> 1;
      const int chalf = (lane & 1) * 16;
      u16x8 o0 = *reinterpret_cast<const u16x8*>(&lt[rl * 40 + chalf]);
      u16x8 o1 = *reinterpret_cast<const u16x8*>(&lt[rl * 40 + chalf + 8]);
      const int m = bm0 + wr + rh * 32 + rl;
      const int n0 = bn0 + wc + cp * 32 + chalf;
      unsigned short* dst = outZ + (size_t)m * Ndim + n0;
      *reinterpret_cast<u16x8*>(dst) = o0;
      *reinterpret_cast<u16x8*>(dst + 8) = o1;
      asm volatile("s_waitcnt lgkmcnt(0)" ::: "memory");
    }
  }
}

// ---------------- banded attention: one wave per (b,h,q), lane = d ----------
__global__ __launch_bounds__(256) void attn_band(const unsigned short* __restrict__ qkv,
                                                 unsigned short* __restrict__ outp) {
  const int gw = blockIdx.x * 4 + (threadIdx.x >> 6);
  const int lane = threadIdx.x & 63;
  const int q = gw & (SEQ - 1);
  const int bh = gw >> 10;
  const int h = bh & (NHEAD - 1);
  const int b = bh >> 4;
  const size_t row0 = (size_t)(b * SEQ + q);
  const size_t stride = 3 * DMODEL;
  const float qv = bf2f(qkv[row0 * stride + h * HDIM + lane]);

  float sc[KBAND];
  float mx = -1e30f;
#pragma unroll
  for (int jj = 0; jj < KBAND; ++jj) {
    const int j = q + jj;
    const int jc = (j < SEQ) ? j : (SEQ - 1);
    float kv = bf2f(qkv[(size_t)(b * SEQ + jc) * stride + DMODEL + h * HDIM + lane]);
    float p = qv * kv;
#pragma unroll
    for (int m = 32; m; m >>= 1) p += __shfl_xor(p, m);
    p *= 0.125f;
    p = (j < SEQ) ? p : -1e30f;
    sc[jj] = p;
    mx = fmaxf(mx, p);
  }
  float denom = 0.f;
  float ov = 0.f;
#pragma unroll
  for (int jj = 0; jj < KBAND; ++jj) {
    const int j = q + jj;
    const int jc = (j < SEQ) ? j : (SEQ - 1);
    float p = __expf(sc[jj] - mx);
    p = (j < SEQ) ? p : 0.f;
    denom += p;
    ov += p * bf2f(qkv[(size_t)(b * SEQ + jc) * stride + 2 * DMODEL + h * HDIM + lane]);
  }
  ov /= denom;
  outp[row0 * DMODEL + h * HDIM + lane] = f2bf(ov);
}

// ---------------- residual(bf16, in-place) + split-K reduce + LayerNorm -----
__global__ __launch_bounds__(256) void add_ln(const float* __restrict__ srcf,
                                              unsigned short* __restrict__ xb,
                                              const unsigned short* __restrict__ part,
                                              int nz,
                                              const float* __restrict__ gw,
                                              const float* __restrict__ gb,
                                              float* __restrict__ outf) {
  const int row = blockIdx.x;
  const int tid = threadIdx.x;
  const size_t slab = (size_t)MROWS * DMODEL;
  unsigned short* xp = xb + (size_t)row * DMODEL;
  const unsigned short* pp = part + (size_t)row * DMODEL;
  float v[4];
  float s = 0.f, s2 = 0.f;
#pragma unroll
  for (int i = 0; i < 4; ++i) {
    const int idx = tid + i * 256;
    float a = srcf ? srcf[(size_t)row * DMODEL + idx] : bf2f(xp[idx]);
    for (int z = 0; z < nz; ++z) a += bf2f(pp[z * slab + idx]);
    v[i] = a;
    s += a;
    s2 += a * a;
  }
#pragma unroll
  for (int m = 32; m; m >>= 1) {
    s += __shfl_xor(s, m);
    s2 += __shfl_xor(s2, m);
  }
  __shared__ float wsm[8];
  const int wave = tid >> 6, lane = tid & 63;
  if (lane == 0) {
    wsm[wave] = s;
    wsm[4 + wave] = s2;
  }
  __syncthreads();
  s = wsm[0] + wsm[1] + wsm[2] + wsm[3];
  s2 = wsm[4] + wsm[5] + wsm[6] + wsm[7];
  const float mean = s * (1.f / DMODEL);
  const float var = s2 * (1.f / DMODEL) - mean * mean;
  const float rstd = rsqrtf(var + 1e-5f);
#pragma unroll
  for (int i = 0; i < 4; ++i) {
    const int idx = tid + i * 256;
    const float y = (v[i] - mean) * rstd * gw[idx] + gb[idx];
    xp[idx] = f2bf(y);
    if (outf) outf[(size_t)row * DMODEL + idx] = y;
  }
}

extern "C" void kernel_launch(void* const* d_in, const int* in_sizes, int n_in,
                              void* d_out, int out_size, void* d_ws, size_t ws_size,
                              hipStream_t stream) {
  const float* src  = (const float*)d_in[0];
  const float* Wqkv = (const float*)d_in[1];
  const float* bqkv = (const float*)d_in[2];
  const float* Wo   = (const float*)d_in[3];
  const float* bo   = (const float*)d_in[4];
  const float* W1   = (const float*)d_in[5];
  const float* b1   = (const float*)d_in[6];
  const float* W2   = (const float*)d_in[7];
  const float* b2   = (const float*)d_in[8];
  const float* ln1w = (const float*)d_in[9];
  const float* ln1b = (const float*)d_in[10];
  const float* ln2w = (const float*)d_in[11];
  const float* ln2b = (const float*)d_in[12];
  float* out = (float*)d_out;

  // workspace carve-up (~168 MB of 209.7 MB)
  char* p = (char*)d_ws;
  unsigned short* wqkv_b = (unsigned short*)p; p += (size_t)LNUM * 3072 * 1024 * 2;
  unsigned short* wo_b   = (unsigned short*)p; p += (size_t)LNUM * 1024 * 1024 * 2;
  unsigned short* w1_b   = (unsigned short*)p; p += (size_t)LNUM * 4096 * 1024 * 2;
  unsigned short* w2_b   = (unsigned short*)p; p += (size_t)LNUM * 1024 * 4096 * 2;
  unsigned short* xb     = (unsigned short*)p; p += (size_t)MROWS * DMODEL * 2;
  // region R: [qkvb 24MB | aob 8MB] aliased by [hb 32MB], then part 4x8MB bf16
  char* R = p;
  unsigned short* qkvb = (unsigned short*)R;
  unsigned short* aob  = (unsigned short*)(R + (size_t)MROWS * 3 * DMODEL * 2);
  unsigned short* hb   = (unsigned short*)R;
  unsigned short* part = (unsigned short*)(R + (size_t)MROWS * 4096 * 2);
  p = R + (size_t)MROWS * 4096 * 2 + (size_t)4 * MROWS * DMODEL * 2;
  if (ws_size < (size_t)(p - (char*)d_ws)) return;

  cvt_bf16<<<(long)LNUM * 3072 * 1024 / 1024, 256, 0, stream>>>(Wqkv, wqkv_b, (long)LNUM * 3072 * 1024);
  cvt_bf16<<<(long)LNUM * 1024 * 1024 / 1024, 256, 0, stream>>>(Wo, wo_b, (long)LNUM * 1024 * 1024);
  cvt_bf16<<<(long)LNUM * 4096 * 1024 / 1024, 256, 0, stream>>>(W1, w1_b, (long)LNUM * 4096 * 1024);
  cvt_bf16<<<(long)LNUM * 1024 * 4096 / 1024, 256, 0, stream>>>(W2, w2_b, (long)LNUM * 1024 * 4096);
  cvt_bf16<<<(long)MROWS * DMODEL / 1024, 256, 0, stream>>>(src, xb, (long)MROWS * DMODEL);

  for (int l = 0; l < LNUM; ++l) {
    // QKV: [4096,1024] x [3072,1024]^T -> bf16 [4096,3072]; 256x128 tile
    gemm256x128<0><<<dim3(3072 / 128, MROWS / 256, 1), 256, 0, stream>>>(
        xb, wqkv_b + (size_t)l * 3072 * 1024, bqkv + l * 3072, qkvb, 3072, 1024, 1024);
    attn_band<<<(BATCH * NHEAD * SEQ) / 4, 256, 0, stream>>>(qkvb, aob);
    // Wo: split-K=2 (Ks=512) -> bf16 partials; 512 blk
    gemm128<2><<<dim3(1024 / 128, MROWS / 128, 2), 256, 0, stream>>>(
        aob, wo_b + (size_t)l * 1024 * 1024, bo + l * 1024, part, 1024, 1024, 512);
    // x = LN(x + p0 + p1); in-place bf16 residual (srcf only on layer 0)
    add_ln<<<MROWS, 256, 0, stream>>>(l == 0 ? src : nullptr, xb, part, 2,
                                      ln1w + l * DMODEL, ln1b + l * DMODEL, nullptr);
    // W1 + gelu: -> bf16 [4096,4096]; 256x128 tile, 512 blk
    gemm256x128<1><<<dim3(FDIM / 128, MROWS / 256, 1), 256, 0, stream>>>(
        xb, w1_b + (size_t)l * 4096 * 1024, b1 + l * FDIM, hb, FDIM, 1024, 1024);
    // W2: split-K=4 (Ks=1024) -> bf16 partials; 1024 blk
    gemm128<2><<<dim3(1024 / 128, MROWS / 128, 4), 256, 0, stream>>>(
        hb, w2_b + (size_t)l * 1024 * 4096, b2 + l * 1024, part, 1024, 4096, 1024);
    // x = LN(x + sum p); final layer also writes f32 d_out
    add_ln<<<MROWS, 256, 0, stream>>>(nullptr, xb, part, 4,
                                      ln2w + l * DMODEL, ln2b + l * DMODEL,
                                      (l == LNUM - 1) ? out : nullptr);
  }
}

// Round 19
// 867.688 us; speedup vs baseline: 1.0683x; 1.0333x over previous
//
#include <hip/hip_runtime.h>

#define LNUM 4
#define DMODEL 1024
#define NHEAD 16
#define FDIM 4096
#define BATCH 4
#define SEQ 1024
#define HDIM 64
#define KBAND 8
#define MROWS (BATCH * SEQ)

typedef __attribute__((ext_vector_type(8))) __bf16 bf16x8;
typedef __attribute__((ext_vector_type(4))) float f32x4;
typedef __attribute__((ext_vector_type(8))) unsigned short u16x8;

__device__ __forceinline__ unsigned short f2bf(float f) {
  unsigned int u = __builtin_bit_cast(unsigned int, f);
  u = u + 0x7fffu + ((u >> 16) & 1u);
  return (unsigned short)(u >> 16);
}
__device__ __forceinline__ float bf2f(unsigned short h) {
  unsigned int u = ((unsigned int)h) << 16;
  return __builtin_bit_cast(float, u);
}

#define GLOAD16(gp, lp)                                                        \
  __builtin_amdgcn_global_load_lds(                                            \
      (const __attribute__((address_space(1))) void*)(gp),                     \
      (__attribute__((address_space(3))) void*)(lp), 16, 0, 0)

// ---------------- fp32 -> bf16 conversion -----------------------------------
__global__ __launch_bounds__(256) void cvt_bf16(const float* __restrict__ in,
                                                unsigned short* __restrict__ out,
                                                long n) {
  long i = ((long)blockIdx.x * 256 + threadIdx.x) * 4;
  if (i + 3 < n) {
    float4 v = *reinterpret_cast<const float4*>(in + i);
    ushort4 o;
    o.x = f2bf(v.x);
    o.y = f2bf(v.y);
    o.z = f2bf(v.z);
    o.w = f2bf(v.w);
    *reinterpret_cast<ushort4*>(out + i) = o;
  }
}

// ---------------- 128x128 bf16 GEMM, BK=64 single-buffer (R16 exact) --------
// CHAMPION config (R16: 866us total; GEMMs ~51us, FETCH 25MB, MfmaUtil 27%,
// conflicts 131K). Measured-closed axes: schedule (6 variants: 2ph-BK64,
// 8ph, 8ph+T2, 2ph-256^2, counted-vmcnt dbuf x2 -> all regress vs drain-0 +
// TLP at these shapes); tile (256^2 1-blk/CU and 256x128 2-blk/CU both lose
// to 128^2 4-blk/CU); BK (32 worse, 64 best). Per iter: stage 8 gload_lds
// (32KB) -> __syncthreads -> 16 ds_read + 32 MFMA -> __syncthreads; latency
// hidden by 3-4 resident blocks/CU (m114 TLP).
// Swizzle for 128B rows: stored (row,g) holds source granule g^((row>>1)&7);
// write side pre-swizzles global source col; read quad = kg^((fr>>1)&7) ->
// conflict-free (m136). 8x8 super-tile under XCD chunking: per-XCD working
// set A(2MB)+B(2MB) = L2 (FETCH 53->25MB). Epilogue: wave-private LDS
// transpose, full 64B-line stores.
// blockIdx.z = K-split (range [z*Ks,(z+1)*Ks)); Ks % 64 == 0.
// EPI: 0 = bf16 (+bias), 1 = bf16 (+bias, exact gelu),
//      2 = bf16 PARTIAL slab per z (bias only z==0).
template <int EPI>
__global__ __launch_bounds__(256, 4) void gemm128(const unsigned short* __restrict__ A,
                                                  const unsigned short* __restrict__ W,
                                                  const float* __restrict__ bias,
                                                  unsigned short* __restrict__ Cout,
                                                  int Ndim, int Kdim, int Ks) {
  __shared__ unsigned short SH[16384];  // As=SH[0:8192], Bs=SH[8192:16384]
  unsigned short* As = SH;
  unsigned short* Bs = SH + 8192;
  const int tid = threadIdx.x;
  const int wave = tid >> 6;
  const int lane = tid & 63;

  // bijective XCD chunked swizzle (m204) + 8x8 super-tile inner order.
  const int gx = gridDim.x, gy = gridDim.y;
  const int nwg = gx * gy;
  const int lin = blockIdx.x + blockIdx.y * gx;
  const int q8 = nwg >> 3, r8 = nwg & 7;
  const int xcd = lin & 7, cidx = lin >> 3;
  const int cbase = (xcd < r8) ? xcd * (q8 + 1) : r8 * (q8 + 1) + (xcd - r8) * q8;
  const int swz = cbase + cidx;
  const int sup = swz >> 6, inn = swz & 63;       // super-tile = 64 wg
  const int sbm = sup % (gy >> 3);
  const int sbn = sup / (gy >> 3);
  const int bm0 = (sbm * 8 + (inn & 7)) * 128;
  const int bn0 = (sbn * 8 + (inn >> 3)) * 128;
  const int kz0 = blockIdx.z * Ks;

  // staging: tile 128r x 64k = 16KB/matrix = 256 thr x 4 instrs x 16B.
  const int r0 = tid >> 3;                               // 0..31
  const int c0 = (((tid & 7) ^ ((tid >> 4) & 7)) << 3);  // swizzled col elem
  const unsigned short* gA = A + (size_t)(bm0 + r0) * Kdim + kz0 + c0;
  const unsigned short* gB = W + (size_t)(bn0 + r0) * Kdim + kz0 + c0;
  const size_t rs32 = (size_t)32 * Kdim;

  f32x4 acc[4][4] = {};

  const int wr = (wave >> 1) * 64;  // wave row origin in tile
  const int wc = (wave & 1) * 64;   // wave col origin in tile
  const int fr = lane & 15;
  const int rkey = (fr >> 1) & 7;   // read-side XOR key

  const int nt = Ks >> 6;
  for (int t = 0; t < nt; ++t) {
#pragma unroll
    for (int i = 0; i < 4; ++i) {
      GLOAD16(gA + i * rs32, &As[i * 2048 + wave * 512]);
      GLOAD16(gB + i * rs32, &Bs[i * 2048 + wave * 512]);
    }
    gA += 64;
    gB += 64;
    __syncthreads();  // drains vmcnt(0): tile staged
#pragma unroll
    for (int ks = 0; ks < 2; ++ks) {
      const int kg0 = (lane >> 4) + 4 * ks;                 // granule 0..7
      const int kofs = ((kg0 ^ rkey) << 3);                 // swizzled elem
      bf16x8 af[4], bfr[4];
#pragma unroll
      for (int i = 0; i < 4; ++i)
        af[i] = *reinterpret_cast<const bf16x8*>(&As[(wr + i * 16 + fr) * 64 + kofs]);
#pragma unroll
      for (int j = 0; j < 4; ++j)
        bfr[j] = *reinterpret_cast<const bf16x8*>(&Bs[(wc + j * 16 + fr) * 64 + kofs]);
#pragma unroll
      for (int i = 0; i < 4; ++i)
#pragma unroll
        for (int j = 0; j < 4; ++j)
          acc[i][j] = __builtin_amdgcn_mfma_f32_16x16x32_bf16(af[i], bfr[j], acc[i][j], 0, 0, 0);
    }
    __syncthreads();  // reads done before next stage overwrites
  }

  // ---- transposed epilogue (R9/R10-verified; LDS reused) ----
  // C/D layout: col = lane&15, row = (lane>>4)*4 + reg (m89/m91).
  const int rr = (lane >> 4) * 4;
  const int cc = lane & 15;
  const bool addb = (EPI != 2) || (blockIdx.z == 0);
  unsigned short* outZ =
      Cout + (EPI == 2 ? (size_t)blockIdx.z * ((size_t)gy * 128) * Ndim : 0);
  float bv[4];
#pragma unroll
  for (int j = 0; j < 4; ++j)
    bv[j] = addb ? bias[bn0 + wc + j * 16 + cc] : 0.0f;

  unsigned short* lt = SH + wave * 1280;  // 2560 B per wave (32 rows x 40 u16)
#pragma unroll
  for (int rh = 0; rh < 2; ++rh) {        // row half: rows rh*32..+31
#pragma unroll
    for (int cp = 0; cp < 2; ++cp) {      // col pair: cols cp*32..+31
#pragma unroll
      for (int ii = 0; ii < 2; ++ii)
#pragma unroll
        for (int jj = 0; jj < 2; ++jj)
#pragma unroll
          for (int r = 0; r < 4; ++r) {
            float v = acc[rh * 2 + ii][cp * 2 + jj][r] + bv[cp * 2 + jj];
            if (EPI == 1) v = 0.5f * v * (1.0f + erff(v * 0.70710678118654752f));
            lt[(ii * 16 + rr + r) * 40 + jj * 16 + cc] = f2bf(v);
          }
      asm volatile("s_waitcnt lgkmcnt(0)" ::: "memory");  // wave-local RAW
      const int rl = lane >> 1;            // local row 0..31
      const int chalf = (lane & 1) * 16;   // col sub-half (16 u16 = 32 B)
      u16x8 o0 = *reinterpret_cast<const u16x8*>(&lt[rl * 40 + chalf]);
      u16x8 o1 = *reinterpret_cast<const u16x8*>(&lt[rl * 40 + chalf + 8]);
      const int m = bm0 + wr + rh * 32 + rl;
      const int n0 = bn0 + wc + cp * 32 + chalf;
      unsigned short* dst = outZ + (size_t)m * Ndim + n0;
      *reinterpret_cast<u16x8*>(dst) = o0;
      *reinterpret_cast<u16x8*>(dst + 8) = o1;
      asm volatile("s_waitcnt lgkmcnt(0)" ::: "memory");  // reads done pre-overwrite
    }
  }
}

// ---------------- banded attention: one wave per (b,h,q), lane = d ----------
__global__ __launch_bounds__(256) void attn_band(const unsigned short* __restrict__ qkv,
                                                 unsigned short* __restrict__ outp) {
  const int gw = blockIdx.x * 4 + (threadIdx.x >> 6);
  const int lane = threadIdx.x & 63;
  const int q = gw & (SEQ - 1);
  const int bh = gw >> 10;
  const int h = bh & (NHEAD - 1);
  const int b = bh >> 4;
  const size_t row0 = (size_t)(b * SEQ + q);
  const size_t stride = 3 * DMODEL;
  const float qv = bf2f(qkv[row0 * stride + h * HDIM + lane]);

  float sc[KBAND];
  float mx = -1e30f;
#pragma unroll
  for (int jj = 0; jj < KBAND; ++jj) {
    const int j = q + jj;
    const int jc = (j < SEQ) ? j : (SEQ - 1);
    float kv = bf2f(qkv[(size_t)(b * SEQ + jc) * stride + DMODEL + h * HDIM + lane]);
    float p = qv * kv;
#pragma unroll
    for (int m = 32; m; m >>= 1) p += __shfl_xor(p, m);
    p *= 0.125f;
    p = (j < SEQ) ? p : -1e30f;
    sc[jj] = p;
    mx = fmaxf(mx, p);
  }
  float denom = 0.f;
  float ov = 0.f;
#pragma unroll
  for (int jj = 0; jj < KBAND; ++jj) {
    const int j = q + jj;
    const int jc = (j < SEQ) ? j : (SEQ - 1);
    float p = __expf(sc[jj] - mx);
    p = (j < SEQ) ? p : 0.f;
    denom += p;
    ov += p * bf2f(qkv[(size_t)(b * SEQ + jc) * stride + 2 * DMODEL + h * HDIM + lane]);
  }
  ov /= denom;
  outp[row0 * DMODEL + h * HDIM + lane] = f2bf(ov);
}

// ---------------- residual(bf16, in-place) + split-K reduce + LayerNorm -----
__global__ __launch_bounds__(256) void add_ln(const float* __restrict__ srcf,
                                              unsigned short* __restrict__ xb,
                                              const unsigned short* __restrict__ part,
                                              int nz,
                                              const float* __restrict__ gw,
                                              const float* __restrict__ gb,
                                              float* __restrict__ outf) {
  const int row = blockIdx.x;
  const int tid = threadIdx.x;
  const size_t slab = (size_t)MROWS * DMODEL;
  unsigned short* xp = xb + (size_t)row * DMODEL;
  const unsigned short* pp = part + (size_t)row * DMODEL;
  float v[4];
  float s = 0.f, s2 = 0.f;
#pragma unroll
  for (int i = 0; i < 4; ++i) {
    const int idx = tid + i * 256;
    float a = srcf ? srcf[(size_t)row * DMODEL + idx] : bf2f(xp[idx]);
    for (int z = 0; z < nz; ++z) a += bf2f(pp[z * slab + idx]);
    v[i] = a;
    s += a;
    s2 += a * a;
  }
#pragma unroll
  for (int m = 32; m; m >>= 1) {
    s += __shfl_xor(s, m);
    s2 += __shfl_xor(s2, m);
  }
  __shared__ float wsm[8];
  const int wave = tid >> 6, lane = tid & 63;
  if (lane == 0) {
    wsm[wave] = s;
    wsm[4 + wave] = s2;
  }
  __syncthreads();
  s = wsm[0] + wsm[1] + wsm[2] + wsm[3];
  s2 = wsm[4] + wsm[5] + wsm[6] + wsm[7];
  const float mean = s * (1.f / DMODEL);
  const float var = s2 * (1.f / DMODEL) - mean * mean;
  const float rstd = rsqrtf(var + 1e-5f);
#pragma unroll
  for (int i = 0; i < 4; ++i) {
    const int idx = tid + i * 256;
    const float y = (v[i] - mean) * rstd * gw[idx] + gb[idx];
    xp[idx] = f2bf(y);
    if (outf) outf[(size_t)row * DMODEL + idx] = y;
  }
}

extern "C" void kernel_launch(void* const* d_in, const int* in_sizes, int n_in,
                              void* d_out, int out_size, void* d_ws, size_t ws_size,
                              hipStream_t stream) {
  const float* src  = (const float*)d_in[0];
  const float* Wqkv = (const float*)d_in[1];
  const float* bqkv = (const float*)d_in[2];
  const float* Wo   = (const float*)d_in[3];
  const float* bo   = (const float*)d_in[4];
  const float* W1   = (const float*)d_in[5];
  const float* b1   = (const float*)d_in[6];
  const float* W2   = (const float*)d_in[7];
  const float* b2   = (const float*)d_in[8];
  const float* ln1w = (const float*)d_in[9];
  const float* ln1b = (const float*)d_in[10];
  const float* ln2w = (const float*)d_in[11];
  const float* ln2b = (const float*)d_in[12];
  float* out = (float*)d_out;

  // workspace carve-up (~168 MB of 209.7 MB)
  char* p = (char*)d_ws;
  unsigned short* wqkv_b = (unsigned short*)p; p += (size_t)LNUM * 3072 * 1024 * 2;
  unsigned short* wo_b   = (unsigned short*)p; p += (size_t)LNUM * 1024 * 1024 * 2;
  unsigned short* w1_b   = (unsigned short*)p; p += (size_t)LNUM * 4096 * 1024 * 2;
  unsigned short* w2_b   = (unsigned short*)p; p += (size_t)LNUM * 1024 * 4096 * 2;
  unsigned short* xb     = (unsigned short*)p; p += (size_t)MROWS * DMODEL * 2;
  // region R: [qkvb 24MB | aob 8MB] aliased by [hb 32MB], then part 4x8MB bf16
  char* R = p;
  unsigned short* qkvb = (unsigned short*)R;
  unsigned short* aob  = (unsigned short*)(R + (size_t)MROWS * 3 * DMODEL * 2);
  unsigned short* hb   = (unsigned short*)R;
  unsigned short* part = (unsigned short*)(R + (size_t)MROWS * 4096 * 2);
  p = R + (size_t)MROWS * 4096 * 2 + (size_t)4 * MROWS * DMODEL * 2;
  if (ws_size < (size_t)(p - (char*)d_ws)) return;

  cvt_bf16<<<(long)LNUM * 3072 * 1024 / 1024, 256, 0, stream>>>(Wqkv, wqkv_b, (long)LNUM * 3072 * 1024);
  cvt_bf16<<<(long)LNUM * 1024 * 1024 / 1024, 256, 0, stream>>>(Wo, wo_b, (long)LNUM * 1024 * 1024);
  cvt_bf16<<<(long)LNUM * 4096 * 1024 / 1024, 256, 0, stream>>>(W1, w1_b, (long)LNUM * 4096 * 1024);
  cvt_bf16<<<(long)LNUM * 1024 * 4096 / 1024, 256, 0, stream>>>(W2, w2_b, (long)LNUM * 1024 * 4096);
  cvt_bf16<<<(long)MROWS * DMODEL / 1024, 256, 0, stream>>>(src, xb, (long)MROWS * DMODEL);

  for (int l = 0; l < LNUM; ++l) {
    // QKV: [4096,1024] x [3072,1024]^T -> bf16 [4096,3072]; 768 blk (3/CU)
    gemm128<0><<<dim3(3072 / 128, MROWS / 128, 1), 256, 0, stream>>>(
        xb, wqkv_b + (size_t)l * 3072 * 1024, bqkv + l * 3072, qkvb, 3072, 1024, 1024);
    attn_band<<<(BATCH * NHEAD * SEQ) / 4, 256, 0, stream>>>(qkvb, aob);
    // Wo: split-K=2 (Ks=512) -> bf16 partials; 512 blk (2/CU)
    gemm128<2><<<dim3(1024 / 128, MROWS / 128, 2), 256, 0, stream>>>(
        aob, wo_b + (size_t)l * 1024 * 1024, bo + l * 1024, part, 1024, 1024, 512);
    // x = LN(x + p0 + p1); in-place bf16 residual (srcf only on layer 0)
    add_ln<<<MROWS, 256, 0, stream>>>(l == 0 ? src : nullptr, xb, part, 2,
                                      ln1w + l * DMODEL, ln1b + l * DMODEL, nullptr);
    // W1 + gelu: -> bf16 [4096,4096]; 1024 blk (4/CU)
    gemm128<1><<<dim3(FDIM / 128, MROWS / 128, 1), 256, 0, stream>>>(
        xb, w1_b + (size_t)l * 4096 * 1024, b1 + l * FDIM, hb, FDIM, 1024, 1024);
    // W2: split-K=4 (Ks=1024) -> bf16 partials; 1024 blk (4/CU)
    gemm128<2><<<dim3(1024 / 128, MROWS / 128, 4), 256, 0, stream>>>(
        hb, w2_b + (size_t)l * 1024 * 4096, b2 + l * 1024, part, 1024, 4096, 1024);
    // x = LN(x + sum p); final layer also writes f32 d_out
    add_ln<<<MROWS, 256, 0, stream>>>(nullptr, xb, part, 4,
                                      ln2w + l * DMODEL, ln2b + l * DMODEL,
                                      (l == LNUM - 1) ? out : nullptr);
  }
}

// Round 20
// 827.361 us; speedup vs baseline: 1.1204x; 1.0487x over previous
//
#include <hip/hip_runtime.h>

#define LNUM 4
#define DMODEL 1024
#define NHEAD 16
#define FDIM 4096
#define BATCH 4
#define SEQ 1024
#define HDIM 64
#define KBAND 8
#define MROWS (BATCH * SEQ)

typedef __attribute__((ext_vector_type(8))) __bf16 bf16x8;
typedef __attribute__((ext_vector_type(4))) float f32x4;
typedef __attribute__((ext_vector_type(8))) unsigned short u16x8;

__device__ __forceinline__ unsigned short f2bf(float f) {
  unsigned int u = __builtin_bit_cast(unsigned int, f);
  u = u + 0x7fffu + ((u >> 16) & 1u);
  return (unsigned short)(u >> 16);
}
__device__ __forceinline__ float bf2f(unsigned short h) {
  unsigned int u = ((unsigned int)h) << 16;
  return __builtin_bit_cast(float, u);
}

#define GLOAD16(gp, lp)                                                        \
  __builtin_amdgcn_global_load_lds(                                            \
      (const __attribute__((address_space(1))) void*)(gp),                     \
      (__attribute__((address_space(3))) void*)(lp), 16, 0, 0)

// ---------------- fused fp32 -> bf16 conversion (all 5 regions, 1 launch) ---
// Destinations are CONTIGUOUS in workspace (wqkv_b|wo_b|w1_b|w2_b|xb), so a
// single sweep writes dst linearly; source region resolved by if-chain.
// Region sizes (elems): 12582912 | 4194304 | 16777216 | 16777216 | 4194304.
#define CVT_O1 12582912L
#define CVT_O2 16777216L
#define CVT_O3 33554432L
#define CVT_O4 50331648L
#define CVT_TOT 54525952L
__global__ __launch_bounds__(256) void cvt_all(const float* __restrict__ s0,
                                               const float* __restrict__ s1,
                                               const float* __restrict__ s2,
                                               const float* __restrict__ s3,
                                               const float* __restrict__ s4,
                                               unsigned short* __restrict__ dst) {
  long i = ((long)blockIdx.x * 256 + threadIdx.x) * 4;
  if (i >= CVT_TOT) return;
  const float* sp;
  if (i < CVT_O1)      sp = s0 + i;
  else if (i < CVT_O2) sp = s1 + (i - CVT_O1);
  else if (i < CVT_O3) sp = s2 + (i - CVT_O2);
  else if (i < CVT_O4) sp = s3 + (i - CVT_O3);
  else                 sp = s4 + (i - CVT_O4);
  float4 v = *reinterpret_cast<const float4*>(sp);
  ushort4 o;
  o.x = f2bf(v.x);
  o.y = f2bf(v.y);
  o.z = f2bf(v.z);
  o.w = f2bf(v.w);
  *reinterpret_cast<ushort4*>(dst + i) = o;
}

// ---------------- 128x128 bf16 GEMM, BK=64 single-buffer (R16 exact) --------
// CHAMPION config (R16/R19: 866-868us total; GEMMs ~50us, FETCH 25MB,
// MfmaUtil 27%, conflicts 131K). Measured-closed axes: schedule (6 variants
// all regress vs drain-0+TLP at these shapes); tile (256^2, 256x128 lose);
// BK (32 worse). Per iter: stage 8 gload_lds (32KB) -> __syncthreads ->
// 16 ds_read + 32 MFMA -> __syncthreads; latency hidden by 3-4 resident
// blocks/CU (m114 TLP). Swizzle for 128B rows: stored (row,g) holds source
// granule g^((row>>1)&7); read quad = kg^((fr>>1)&7) -> conflict-free.
// 8x8 super-tile under XCD chunking: per-XCD working set = L2 (FETCH
// 53->25MB). Epilogue: wave-private LDS transpose, full 64B-line stores.
// blockIdx.z = K-split; EPI: 0 bf16+bias, 1 bf16+bias+gelu, 2 bf16 partial.
template <int EPI>
__global__ __launch_bounds__(256, 4) void gemm128(const unsigned short* __restrict__ A,
                                                  const unsigned short* __restrict__ W,
                                                  const float* __restrict__ bias,
                                                  unsigned short* __restrict__ Cout,
                                                  int Ndim, int Kdim, int Ks) {
  __shared__ unsigned short SH[16384];  // As=SH[0:8192], Bs=SH[8192:16384]
  unsigned short* As = SH;
  unsigned short* Bs = SH + 8192;
  const int tid = threadIdx.x;
  const int wave = tid >> 6;
  const int lane = tid & 63;

  const int gx = gridDim.x, gy = gridDim.y;
  const int nwg = gx * gy;
  const int lin = blockIdx.x + blockIdx.y * gx;
  const int q8 = nwg >> 3, r8 = nwg & 7;
  const int xcd = lin & 7, cidx = lin >> 3;
  const int cbase = (xcd < r8) ? xcd * (q8 + 1) : r8 * (q8 + 1) + (xcd - r8) * q8;
  const int swz = cbase + cidx;
  const int sup = swz >> 6, inn = swz & 63;       // super-tile = 64 wg
  const int sbm = sup % (gy >> 3);
  const int sbn = sup / (gy >> 3);
  const int bm0 = (sbm * 8 + (inn & 7)) * 128;
  const int bn0 = (sbn * 8 + (inn >> 3)) * 128;
  const int kz0 = blockIdx.z * Ks;

  const int r0 = tid >> 3;                               // 0..31
  const int c0 = (((tid & 7) ^ ((tid >> 4) & 7)) << 3);  // swizzled col elem
  const unsigned short* gA = A + (size_t)(bm0 + r0) * Kdim + kz0 + c0;
  const unsigned short* gB = W + (size_t)(bn0 + r0) * Kdim + kz0 + c0;
  const size_t rs32 = (size_t)32 * Kdim;

  f32x4 acc[4][4] = {};

  const int wr = (wave >> 1) * 64;
  const int wc = (wave & 1) * 64;
  const int fr = lane & 15;
  const int rkey = (fr >> 1) & 7;

  const int nt = Ks >> 6;
  for (int t = 0; t < nt; ++t) {
#pragma unroll
    for (int i = 0; i < 4; ++i) {
      GLOAD16(gA + i * rs32, &As[i * 2048 + wave * 512]);
      GLOAD16(gB + i * rs32, &Bs[i * 2048 + wave * 512]);
    }
    gA += 64;
    gB += 64;
    __syncthreads();
#pragma unroll
    for (int ks = 0; ks < 2; ++ks) {
      const int kg0 = (lane >> 4) + 4 * ks;
      const int kofs = ((kg0 ^ rkey) << 3);
      bf16x8 af[4], bfr[4];
#pragma unroll
      for (int i = 0; i < 4; ++i)
        af[i] = *reinterpret_cast<const bf16x8*>(&As[(wr + i * 16 + fr) * 64 + kofs]);
#pragma unroll
      for (int j = 0; j < 4; ++j)
        bfr[j] = *reinterpret_cast<const bf16x8*>(&Bs[(wc + j * 16 + fr) * 64 + kofs]);
#pragma unroll
      for (int i = 0; i < 4; ++i)
#pragma unroll
        for (int j = 0; j < 4; ++j)
          acc[i][j] = __builtin_amdgcn_mfma_f32_16x16x32_bf16(af[i], bfr[j], acc[i][j], 0, 0, 0);
    }
    __syncthreads();
  }

  const int rr = (lane >> 4) * 4;
  const int cc = lane & 15;
  const bool addb = (EPI != 2) || (blockIdx.z == 0);
  unsigned short* outZ =
      Cout + (EPI == 2 ? (size_t)blockIdx.z * ((size_t)gy * 128) * Ndim : 0);
  float bv[4];
#pragma unroll
  for (int j = 0; j < 4; ++j)
    bv[j] = addb ? bias[bn0 + wc + j * 16 + cc] : 0.0f;

  unsigned short* lt = SH + wave * 1280;
#pragma unroll
  for (int rh = 0; rh < 2; ++rh) {
#pragma unroll
    for (int cp = 0; cp < 2; ++cp) {
#pragma unroll
      for (int ii = 0; ii < 2; ++ii)
#pragma unroll
        for (int jj = 0; jj < 2; ++jj)
#pragma unroll
          for (int r = 0; r < 4; ++r) {
            float v = acc[rh * 2 + ii][cp * 2 + jj][r] + bv[cp * 2 + jj];
            if (EPI == 1) v = 0.5f * v * (1.0f + erff(v * 0.70710678118654752f));
            lt[(ii * 16 + rr + r) * 40 + jj * 16 + cc] = f2bf(v);
          }
      asm volatile("s_waitcnt lgkmcnt(0)" ::: "memory");
      const int rl = lane >> 1;
      const int chalf = (lane & 1) * 16;
      u16x8 o0 = *reinterpret_cast<const u16x8*>(&lt[rl * 40 + chalf]);
      u16x8 o1 = *reinterpret_cast<const u16x8*>(&lt[rl * 40 + chalf + 8]);
      const int m = bm0 + wr + rh * 32 + rl;
      const int n0 = bn0 + wc + cp * 32 + chalf;
      unsigned short* dst = outZ + (size_t)m * Ndim + n0;
      *reinterpret_cast<u16x8*>(dst) = o0;
      *reinterpret_cast<u16x8*>(dst + 8) = o1;
      asm volatile("s_waitcnt lgkmcnt(0)" ::: "memory");
    }
  }
}

// ---------------- banded attention: one wave per (b,h,q), lane = d ----------
__global__ __launch_bounds__(256) void attn_band(const unsigned short* __restrict__ qkv,
                                                 unsigned short* __restrict__ outp) {
  const int gw = blockIdx.x * 4 + (threadIdx.x >> 6);
  const int lane = threadIdx.x & 63;
  const int q = gw & (SEQ - 1);
  const int bh = gw >> 10;
  const int h = bh & (NHEAD - 1);
  const int b = bh >> 4;
  const size_t row0 = (size_t)(b * SEQ + q);
  const size_t stride = 3 * DMODEL;
  const float qv = bf2f(qkv[row0 * stride + h * HDIM + lane]);

  float sc[KBAND];
  float mx = -1e30f;
#pragma unroll
  for (int jj = 0; jj < KBAND; ++jj) {
    const int j = q + jj;
    const int jc = (j < SEQ) ? j : (SEQ - 1);
    float kv = bf2f(qkv[(size_t)(b * SEQ + jc) * stride + DMODEL + h * HDIM + lane]);
    float p = qv * kv;
#pragma unroll
    for (int m = 32; m; m >>= 1) p += __shfl_xor(p, m);
    p *= 0.125f;
    p = (j < SEQ) ? p : -1e30f;
    sc[jj] = p;
    mx = fmaxf(mx, p);
  }
  float denom = 0.f;
  float ov = 0.f;
#pragma unroll
  for (int jj = 0; jj < KBAND; ++jj) {
    const int j = q + jj;
    const int jc = (j < SEQ) ? j : (SEQ - 1);
    float p = __expf(sc[jj] - mx);
    p = (j < SEQ) ? p : 0.f;
    denom += p;
    ov += p * bf2f(qkv[(size_t)(b * SEQ + jc) * stride + 2 * DMODEL + h * HDIM + lane]);
  }
  ov /= denom;
  outp[row0 * DMODEL + h * HDIM + lane] = f2bf(ov);
}

// ---------------- residual(bf16, in-place) + split-K reduce + LayerNorm -----
// NZ templated (unrolled partial reduce). resid = srcf (layer 0) else xb.
template <int NZ>
__global__ __launch_bounds__(256) void add_ln(const float* __restrict__ srcf,
                                              unsigned short* __restrict__ xb,
                                              const unsigned short* __restrict__ part,
                                              const float* __restrict__ gw,
                                              const float* __restrict__ gb,
                                              float* __restrict__ outf) {
  const int row = blockIdx.x;
  const int tid = threadIdx.x;
  const size_t slab = (size_t)MROWS * DMODEL;
  unsigned short* xp = xb + (size_t)row * DMODEL;
  const unsigned short* pp = part + (size_t)row * DMODEL;
  float v[4];
  float s = 0.f, s2 = 0.f;
#pragma unroll
  for (int i = 0; i < 4; ++i) {
    const int idx = tid + i * 256;
    float a = srcf ? srcf[(size_t)row * DMODEL + idx] : bf2f(xp[idx]);
#pragma unroll
    for (int z = 0; z < NZ; ++z) a += bf2f(pp[z * slab + idx]);
    v[i] = a;
    s += a;
    s2 += a * a;
  }
#pragma unroll
  for (int m = 32; m; m >>= 1) {
    s += __shfl_xor(s, m);
    s2 += __shfl_xor(s2, m);
  }
  __shared__ float wsm[8];
  const int wave = tid >> 6, lane = tid & 63;
  if (lane == 0) {
    wsm[wave] = s;
    wsm[4 + wave] = s2;
  }
  __syncthreads();
  s = wsm[0] + wsm[1] + wsm[2] + wsm[3];
  s2 = wsm[4] + wsm[5] + wsm[6] + wsm[7];
  const float mean = s * (1.f / DMODEL);
  const float var = s2 * (1.f / DMODEL) - mean * mean;
  const float rstd = rsqrtf(var + 1e-5f);
#pragma unroll
  for (int i = 0; i < 4; ++i) {
    const int idx = tid + i * 256;
    const float y = (v[i] - mean) * rstd * gw[idx] + gb[idx];
    xp[idx] = f2bf(y);
    if (outf) outf[(size_t)row * DMODEL + idx] = y;
  }
}

extern "C" void kernel_launch(void* const* d_in, const int* in_sizes, int n_in,
                              void* d_out, int out_size, void* d_ws, size_t ws_size,
                              hipStream_t stream) {
  const float* src  = (const float*)d_in[0];
  const float* Wqkv = (const float*)d_in[1];
  const float* bqkv = (const float*)d_in[2];
  const float* Wo   = (const float*)d_in[3];
  const float* bo   = (const float*)d_in[4];
  const float* W1   = (const float*)d_in[5];
  const float* b1   = (const float*)d_in[6];
  const float* W2   = (const float*)d_in[7];
  const float* b2   = (const float*)d_in[8];
  const float* ln1w = (const float*)d_in[9];
  const float* ln1b = (const float*)d_in[10];
  const float* ln2w = (const float*)d_in[11];
  const float* ln2b = (const float*)d_in[12];
  float* out = (float*)d_out;

  // workspace carve-up (~168 MB of 209.7 MB). NOTE: wqkv_b..xb CONTIGUOUS
  // (cvt_all writes them as one linear sweep).
  char* p = (char*)d_ws;
  unsigned short* wqkv_b = (unsigned short*)p; p += (size_t)LNUM * 3072 * 1024 * 2;
  unsigned short* wo_b   = (unsigned short*)p; p += (size_t)LNUM * 1024 * 1024 * 2;
  unsigned short* w1_b   = (unsigned short*)p; p += (size_t)LNUM * 4096 * 1024 * 2;
  unsigned short* w2_b   = (unsigned short*)p; p += (size_t)LNUM * 1024 * 4096 * 2;
  unsigned short* xb     = (unsigned short*)p; p += (size_t)MROWS * DMODEL * 2;
  // region R: [qkvb 24MB | aob 8MB] aliased by [hb 32MB], then part 4x8MB bf16
  char* R = p;
  unsigned short* qkvb = (unsigned short*)R;
  unsigned short* aob  = (unsigned short*)(R + (size_t)MROWS * 3 * DMODEL * 2);
  unsigned short* hb   = (unsigned short*)R;
  unsigned short* part = (unsigned short*)(R + (size_t)MROWS * 4096 * 2);
  p = R + (size_t)MROWS * 4096 * 2 + (size_t)4 * MROWS * DMODEL * 2;
  if (ws_size < (size_t)(p - (char*)d_ws)) return;

  // single fused conversion sweep: Wqkv|Wo|W1|W2|src -> contiguous bf16
  cvt_all<<<(CVT_TOT / 4 + 255) / 256, 256, 0, stream>>>(Wqkv, Wo, W1, W2, src, wqkv_b);

  for (int l = 0; l < LNUM; ++l) {
    // QKV: [4096,1024] x [3072,1024]^T -> bf16 [4096,3072]; 768 blk (3/CU)
    gemm128<0><<<dim3(3072 / 128, MROWS / 128, 1), 256, 0, stream>>>(
        xb, wqkv_b + (size_t)l * 3072 * 1024, bqkv + l * 3072, qkvb, 3072, 1024, 1024);
    attn_band<<<(BATCH * NHEAD * SEQ) / 4, 256, 0, stream>>>(qkvb, aob);
    // Wo: split-K=2 (Ks=512) -> bf16 partials; 512 blk (2/CU)
    gemm128<2><<<dim3(1024 / 128, MROWS / 128, 2), 256, 0, stream>>>(
        aob, wo_b + (size_t)l * 1024 * 1024, bo + l * 1024, part, 1024, 1024, 512);
    // x = LN(x + p0 + p1); in-place bf16 residual (srcf only on layer 0)
    add_ln<2><<<MROWS, 256, 0, stream>>>(l == 0 ? src : nullptr, xb, part,
                                         ln1w + l * DMODEL, ln1b + l * DMODEL, nullptr);
    // W1 + gelu: -> bf16 [4096,4096]; 1024 blk (4/CU)
    gemm128<1><<<dim3(FDIM / 128, MROWS / 128, 1), 256, 0, stream>>>(
        xb, w1_b + (size_t)l * 4096 * 1024, b1 + l * FDIM, hb, FDIM, 1024, 1024);
    // W2: split-K=4 (Ks=1024) -> bf16 partials; 1024 blk (4/CU)
    gemm128<2><<<dim3(1024 / 128, MROWS / 128, 4), 256, 0, stream>>>(
        hb, w2_b + (size_t)l * 1024 * 4096, b2 + l * 1024, part, 1024, 4096, 1024);
    // x = LN(x + sum p); final layer also writes f32 d_out
    add_ln<4><<<MROWS, 256, 0, stream>>>(nullptr, xb, part,
                                         ln2w + l * DMODEL, ln2b + l * DMODEL,
                                         (l == LNUM - 1) ? out : nullptr);
  }
}

// Round 21
// 821.850 us; speedup vs baseline: 1.1279x; 1.0067x over previous
//
#include <hip/hip_runtime.h>

#define LNUM 4
#define DMODEL 1024
#define NHEAD 16
#define FDIM 4096
#define BATCH 4
#define SEQ 1024
#define HDIM 64
#define KBAND 8
#define MROWS (BATCH * SEQ)

typedef __attribute__((ext_vector_type(8))) __bf16 bf16x8;
typedef __attribute__((ext_vector_type(4))) float f32x4;
typedef __attribute__((ext_vector_type(8))) unsigned short u16x8;

__device__ __forceinline__ unsigned short f2bf(float f) {
  unsigned int u = __builtin_bit_cast(unsigned int, f);
  u = u + 0x7fffu + ((u >> 16) & 1u);
  return (unsigned short)(u >> 16);
}
__device__ __forceinline__ float bf2f(unsigned short h) {
  unsigned int u = ((unsigned int)h) << 16;
  return __builtin_bit_cast(float, u);
}

#define GLOAD16(gp, lp)                                                        \
  __builtin_amdgcn_global_load_lds(                                            \
      (const __attribute__((address_space(1))) void*)(gp),                     \
      (__attribute__((address_space(3))) void*)(lp), 16, 0, 0)

// ---------------- fused fp32 -> bf16 conversion (all 5 regions, 1 launch) ---
// R21: grid-stride, 8 elems/thread (2x float4 load 32B + 1x u16x8 store 16B),
// 2048 blocks (G11/G13): R20's 4-elem 53k-block version ran at 2.8 TB/s
// (issue/launch-granularity bound, VALUBusy 7.7%). Region offsets are
// multiples of 8 -> chunks never straddle sources.
#define CVT_O1 12582912L
#define CVT_O2 16777216L
#define CVT_O3 33554432L
#define CVT_O4 50331648L
#define CVT_TOT 54525952L
__global__ __launch_bounds__(256) void cvt_all(const float* __restrict__ s0,
                                               const float* __restrict__ s1,
                                               const float* __restrict__ s2,
                                               const float* __restrict__ s3,
                                               const float* __restrict__ s4,
                                               unsigned short* __restrict__ dst) {
  const long stride = (long)gridDim.x * 256 * 8;
  for (long i = ((long)blockIdx.x * 256 + threadIdx.x) * 8; i < CVT_TOT;
       i += stride) {
    const float* sp;
    if (i < CVT_O1)      sp = s0 + i;
    else if (i < CVT_O2) sp = s1 + (i - CVT_O1);
    else if (i < CVT_O3) sp = s2 + (i - CVT_O2);
    else if (i < CVT_O4) sp = s3 + (i - CVT_O3);
    else                 sp = s4 + (i - CVT_O4);
    float4 v0 = *reinterpret_cast<const float4*>(sp);
    float4 v1 = *reinterpret_cast<const float4*>(sp + 4);
    u16x8 o;
    o[0] = f2bf(v0.x); o[1] = f2bf(v0.y); o[2] = f2bf(v0.z); o[3] = f2bf(v0.w);
    o[4] = f2bf(v1.x); o[5] = f2bf(v1.y); o[6] = f2bf(v1.z); o[7] = f2bf(v1.w);
    *reinterpret_cast<u16x8*>(dst + i) = o;
  }
}

// ---------------- 128x128 bf16 GEMM, BK=64 single-buffer (R16 exact) --------
// CHAMPION config (R16/R19/R20: 827-868us total; GEMMs ~50us, FETCH 25MB,
// MfmaUtil 27%, conflicts 131K). Measured-closed axes: schedule (6 variants
// all regress vs drain-0+TLP at these shapes); tile (256^2, 256x128 lose);
// BK (32 worse). Per iter: stage 8 gload_lds (32KB) -> __syncthreads ->
// 16 ds_read + 32 MFMA -> __syncthreads; latency hidden by 3-4 resident
// blocks/CU (m114 TLP). Swizzle for 128B rows: stored (row,g) holds source
// granule g^((row>>1)&7); read quad = kg^((fr>>1)&7) -> conflict-free.
// 8x8 super-tile under XCD chunking: per-XCD working set = L2 (FETCH
// 53->25MB). Epilogue: wave-private LDS transpose, full 64B-line stores.
// blockIdx.z = K-split; EPI: 0 bf16+bias, 1 bf16+bias+gelu, 2 bf16 partial.
template <int EPI>
__global__ __launch_bounds__(256, 4) void gemm128(const unsigned short* __restrict__ A,
                                                  const unsigned short* __restrict__ W,
                                                  const float* __restrict__ bias,
                                                  unsigned short* __restrict__ Cout,
                                                  int Ndim, int Kdim, int Ks) {
  __shared__ unsigned short SH[16384];  // As=SH[0:8192], Bs=SH[8192:16384]
  unsigned short* As = SH;
  unsigned short* Bs = SH + 8192;
  const int tid = threadIdx.x;
  const int wave = tid >> 6;
  const int lane = tid & 63;

  const int gx = gridDim.x, gy = gridDim.y;
  const int nwg = gx * gy;
  const int lin = blockIdx.x + blockIdx.y * gx;
  const int q8 = nwg >> 3, r8 = nwg & 7;
  const int xcd = lin & 7, cidx = lin >> 3;
  const int cbase = (xcd < r8) ? xcd * (q8 + 1) : r8 * (q8 + 1) + (xcd - r8) * q8;
  const int swz = cbase + cidx;
  const int sup = swz >> 6, inn = swz & 63;       // super-tile = 64 wg
  const int sbm = sup % (gy >> 3);
  const int sbn = sup / (gy >> 3);
  const int bm0 = (sbm * 8 + (inn & 7)) * 128;
  const int bn0 = (sbn * 8 + (inn >> 3)) * 128;
  const int kz0 = blockIdx.z * Ks;

  const int r0 = tid >> 3;                               // 0..31
  const int c0 = (((tid & 7) ^ ((tid >> 4) & 7)) << 3);  // swizzled col elem
  const unsigned short* gA = A + (size_t)(bm0 + r0) * Kdim + kz0 + c0;
  const unsigned short* gB = W + (size_t)(bn0 + r0) * Kdim + kz0 + c0;
  const size_t rs32 = (size_t)32 * Kdim;

  f32x4 acc[4][4] = {};

  const int wr = (wave >> 1) * 64;
  const int wc = (wave & 1) * 64;
  const int fr = lane & 15;
  const int rkey = (fr >> 1) & 7;

  const int nt = Ks >> 6;
  for (int t = 0; t < nt; ++t) {
#pragma unroll
    for (int i = 0; i < 4; ++i) {
      GLOAD16(gA + i * rs32, &As[i * 2048 + wave * 512]);
      GLOAD16(gB + i * rs32, &Bs[i * 2048 + wave * 512]);
    }
    gA += 64;
    gB += 64;
    __syncthreads();
#pragma unroll
    for (int ks = 0; ks < 2; ++ks) {
      const int kg0 = (lane >> 4) + 4 * ks;
      const int kofs = ((kg0 ^ rkey) << 3);
      bf16x8 af[4], bfr[4];
#pragma unroll
      for (int i = 0; i < 4; ++i)
        af[i] = *reinterpret_cast<const bf16x8*>(&As[(wr + i * 16 + fr) * 64 + kofs]);
#pragma unroll
      for (int j = 0; j < 4; ++j)
        bfr[j] = *reinterpret_cast<const bf16x8*>(&Bs[(wc + j * 16 + fr) * 64 + kofs]);
#pragma unroll
      for (int i = 0; i < 4; ++i)
#pragma unroll
        for (int j = 0; j < 4; ++j)
          acc[i][j] = __builtin_amdgcn_mfma_f32_16x16x32_bf16(af[i], bfr[j], acc[i][j], 0, 0, 0);
    }
    __syncthreads();
  }

  const int rr = (lane >> 4) * 4;
  const int cc = lane & 15;
  const bool addb = (EPI != 2) || (blockIdx.z == 0);
  unsigned short* outZ =
      Cout + (EPI == 2 ? (size_t)blockIdx.z * ((size_t)gy * 128) * Ndim : 0);
  float bv[4];
#pragma unroll
  for (int j = 0; j < 4; ++j)
    bv[j] = addb ? bias[bn0 + wc + j * 16 + cc] : 0.0f;

  unsigned short* lt = SH + wave * 1280;
#pragma unroll
  for (int rh = 0; rh < 2; ++rh) {
#pragma unroll
    for (int cp = 0; cp < 2; ++cp) {
#pragma unroll
      for (int ii = 0; ii < 2; ++ii)
#pragma unroll
        for (int jj = 0; jj < 2; ++jj)
#pragma unroll
          for (int r = 0; r < 4; ++r) {
            float v = acc[rh * 2 + ii][cp * 2 + jj][r] + bv[cp * 2 + jj];
            if (EPI == 1) v = 0.5f * v * (1.0f + erff(v * 0.70710678118654752f));
            lt[(ii * 16 + rr + r) * 40 + jj * 16 + cc] = f2bf(v);
          }
      asm volatile("s_waitcnt lgkmcnt(0)" ::: "memory");
      const int rl = lane >> 1;
      const int chalf = (lane & 1) * 16;
      u16x8 o0 = *reinterpret_cast<const u16x8*>(&lt[rl * 40 + chalf]);
      u16x8 o1 = *reinterpret_cast<const u16x8*>(&lt[rl * 40 + chalf + 8]);
      const int m = bm0 + wr + rh * 32 + rl;
      const int n0 = bn0 + wc + cp * 32 + chalf;
      unsigned short* dst = outZ + (size_t)m * Ndim + n0;
      *reinterpret_cast<u16x8*>(dst) = o0;
      *reinterpret_cast<u16x8*>(dst + 8) = o1;
      asm volatile("s_waitcnt lgkmcnt(0)" ::: "memory");
    }
  }
}

// ---------------- banded attention: one wave per (b,h,q), lane = d ----------
__global__ __launch_bounds__(256) void attn_band(const unsigned short* __restrict__ qkv,
                                                 unsigned short* __restrict__ outp) {
  const int gw = blockIdx.x * 4 + (threadIdx.x >> 6);
  const int lane = threadIdx.x & 63;
  const int q = gw & (SEQ - 1);
  const int bh = gw >> 10;
  const int h = bh & (NHEAD - 1);
  const int b = bh >> 4;
  const size_t row0 = (size_t)(b * SEQ + q);
  const size_t stride = 3 * DMODEL;
  const float qv = bf2f(qkv[row0 * stride + h * HDIM + lane]);

  float sc[KBAND];
  float mx = -1e30f;
#pragma unroll
  for (int jj = 0; jj < KBAND; ++jj) {
    const int j = q + jj;
    const int jc = (j < SEQ) ? j : (SEQ - 1);
    float kv = bf2f(qkv[(size_t)(b * SEQ + jc) * stride + DMODEL + h * HDIM + lane]);
    float p = qv * kv;
#pragma unroll
    for (int m = 32; m; m >>= 1) p += __shfl_xor(p, m);
    p *= 0.125f;
    p = (j < SEQ) ? p : -1e30f;
    sc[jj] = p;
    mx = fmaxf(mx, p);
  }
  float denom = 0.f;
  float ov = 0.f;
#pragma unroll
  for (int jj = 0; jj < KBAND; ++jj) {
    const int j = q + jj;
    const int jc = (j < SEQ) ? j : (SEQ - 1);
    float p = __expf(sc[jj] - mx);
    p = (j < SEQ) ? p : 0.f;
    denom += p;
    ov += p * bf2f(qkv[(size_t)(b * SEQ + jc) * stride + 2 * DMODEL + h * HDIM + lane]);
  }
  ov /= denom;
  outp[row0 * DMODEL + h * HDIM + lane] = f2bf(ov);
}

// ---------------- residual(bf16, in-place) + split-K reduce + LayerNorm -----
template <int NZ>
__global__ __launch_bounds__(256) void add_ln(const float* __restrict__ srcf,
                                              unsigned short* __restrict__ xb,
                                              const unsigned short* __restrict__ part,
                                              const float* __restrict__ gw,
                                              const float* __restrict__ gb,
                                              float* __restrict__ outf) {
  const int row = blockIdx.x;
  const int tid = threadIdx.x;
  const size_t slab = (size_t)MROWS * DMODEL;
  unsigned short* xp = xb + (size_t)row * DMODEL;
  const unsigned short* pp = part + (size_t)row * DMODEL;
  float v[4];
  float s = 0.f, s2 = 0.f;
#pragma unroll
  for (int i = 0; i < 4; ++i) {
    const int idx = tid + i * 256;
    float a = srcf ? srcf[(size_t)row * DMODEL + idx] : bf2f(xp[idx]);
#pragma unroll
    for (int z = 0; z < NZ; ++z) a += bf2f(pp[z * slab + idx]);
    v[i] = a;
    s += a;
    s2 += a * a;
  }
#pragma unroll
  for (int m = 32; m; m >>= 1) {
    s += __shfl_xor(s, m);
    s2 += __shfl_xor(s2, m);
  }
  __shared__ float wsm[8];
  const int wave = tid >> 6, lane = tid & 63;
  if (lane == 0) {
    wsm[wave] = s;
    wsm[4 + wave] = s2;
  }
  __syncthreads();
  s = wsm[0] + wsm[1] + wsm[2] + wsm[3];
  s2 = wsm[4] + wsm[5] + wsm[6] + wsm[7];
  const float mean = s * (1.f / DMODEL);
  const float var = s2 * (1.f / DMODEL) - mean * mean;
  const float rstd = rsqrtf(var + 1e-5f);
#pragma unroll
  for (int i = 0; i < 4; ++i) {
    const int idx = tid + i * 256;
    const float y = (v[i] - mean) * rstd * gw[idx] + gb[idx];
    xp[idx] = f2bf(y);
    if (outf) outf[(size_t)row * DMODEL + idx] = y;
  }
}

extern "C" void kernel_launch(void* const* d_in, const int* in_sizes, int n_in,
                              void* d_out, int out_size, void* d_ws, size_t ws_size,
                              hipStream_t stream) {
  const float* src  = (const float*)d_in[0];
  const float* Wqkv = (const float*)d_in[1];
  const float* bqkv = (const float*)d_in[2];
  const float* Wo   = (const float*)d_in[3];
  const float* bo   = (const float*)d_in[4];
  const float* W1   = (const float*)d_in[5];
  const float* b1   = (const float*)d_in[6];
  const float* W2   = (const float*)d_in[7];
  const float* b2   = (const float*)d_in[8];
  const float* ln1w = (const float*)d_in[9];
  const float* ln1b = (const float*)d_in[10];
  const float* ln2w = (const float*)d_in[11];
  const float* ln2b = (const float*)d_in[12];
  float* out = (float*)d_out;

  // workspace carve-up (~168 MB of 209.7 MB). wqkv_b..xb CONTIGUOUS.
  char* p = (char*)d_ws;
  unsigned short* wqkv_b = (unsigned short*)p; p += (size_t)LNUM * 3072 * 1024 * 2;
  unsigned short* wo_b   = (unsigned short*)p; p += (size_t)LNUM * 1024 * 1024 * 2;
  unsigned short* w1_b   = (unsigned short*)p; p += (size_t)LNUM * 4096 * 1024 * 2;
  unsigned short* w2_b   = (unsigned short*)p; p += (size_t)LNUM * 1024 * 4096 * 2;
  unsigned short* xb     = (unsigned short*)p; p += (size_t)MROWS * DMODEL * 2;
  char* R = p;
  unsigned short* qkvb = (unsigned short*)R;
  unsigned short* aob  = (unsigned short*)(R + (size_t)MROWS * 3 * DMODEL * 2);
  unsigned short* hb   = (unsigned short*)R;
  unsigned short* part = (unsigned short*)(R + (size_t)MROWS * 4096 * 2);
  p = R + (size_t)MROWS * 4096 * 2 + (size_t)4 * MROWS * DMODEL * 2;
  if (ws_size < (size_t)(p - (char*)d_ws)) return;

  // single fused conversion sweep: Wqkv|Wo|W1|W2|src -> contiguous bf16
  cvt_all<<<2048, 256, 0, stream>>>(Wqkv, Wo, W1, W2, src, wqkv_b);

  for (int l = 0; l < LNUM; ++l) {
    gemm128<0><<<dim3(3072 / 128, MROWS / 128, 1), 256, 0, stream>>>(
        xb, wqkv_b + (size_t)l * 3072 * 1024, bqkv + l * 3072, qkvb, 3072, 1024, 1024);
    attn_band<<<(BATCH * NHEAD * SEQ) / 4, 256, 0, stream>>>(qkvb, aob);
    gemm128<2><<<dim3(1024 / 128, MROWS / 128, 2), 256, 0, stream>>>(
        aob, wo_b + (size_t)l * 1024 * 1024, bo + l * 1024, part, 1024, 1024, 512);
    add_ln<2><<<MROWS, 256, 0, stream>>>(l == 0 ? src : nullptr, xb, part,
                                         ln1w + l * DMODEL, ln1b + l * DMODEL, nullptr);
    gemm128<1><<<dim3(FDIM / 128, MROWS / 128, 1), 256, 0, stream>>>(
        xb, w1_b + (size_t)l * 4096 * 1024, b1 + l * FDIM, hb, FDIM, 1024, 1024);
    gemm128<2><<<dim3(1024 / 128, MROWS / 128, 4), 256, 0, stream>>>(
        hb, w2_b + (size_t)l * 1024 * 4096, b2 + l * 1024, part, 1024, 4096, 1024);
    add_ln<4><<<MROWS, 256, 0, stream>>>(nullptr, xb, part,
                                         ln2w + l * DMODEL, ln2b + l * DMODEL,
                                         (l == LNUM - 1) ? out : nullptr);
  }
}